// Round 16
// baseline (1360.150 us; speedup 1.0000x reference)
//
#include <hip/hip_runtime.h>
#include <hip/hip_bf16.h>
#include <hip/hip_fp16.h>

#define NN 25000
#define KK 16
#define EE 400000
#define DD 12
#define UU 48
#define EPSBN 1e-5f
#define RP 88    // LDS row stride for B-tiles in k_edge/heads (halfwords)
#define RPN 72   // LDS row stride in k_node
#define RPA 72   // LDS row stride for k_edge A-tiles

using bf16 = __hip_bfloat16;
typedef short bf16x8 __attribute__((ext_vector_type(8)));
typedef short sx8 __attribute__((ext_vector_type(8)));
typedef float f32x4 __attribute__((ext_vector_type(4)));

__device__ __forceinline__ float b2f(bf16 v){ return __bfloat162float(v); }
__device__ __forceinline__ float sigm(float x){ return 1.f/(1.f+__expf(-x)); }
__device__ __forceinline__ float siluf(float x){ return x/(1.f+__expf(-x)); }
__device__ __forceinline__ short f2bs(float f){ bf16 h=__float2bfloat16(f); return *(short*)&h; }
__device__ __forceinline__ float bs2f(short s){ bf16 h; *(short*)&h = s; return __bfloat162float(h); }
__device__ __forceinline__ short f2hs(float f){ __half h=__float2half(f); return *(short*)&h; }
__device__ __forceinline__ float hs2f(short s){ __half h; *(short*)&h = s; return __half2float(h); }

__device__ __forceinline__ float ldx(const void* p, size_t i, bool isb){
  return isb ? b2f(((const bf16*)p)[i]) : ((const float*)p)[i];
}
__device__ __forceinline__ void stout(void* p, size_t i, float v, bool isb){
  if (isb) ((bf16*)p)[i] = __float2bfloat16(v);
  else     ((float*)p)[i] = v;
}
__device__ __forceinline__ bool dflag(const void* vbng){
  return *((const unsigned*)vbng) == 0x3F803F80u;
}
#define LDSFENCE() asm volatile("s_waitcnt lgkmcnt(0)" ::: "memory")

__device__ __forceinline__ void stageW(short* BT, const void* W, size_t WOFF, bool isb, int tid, int rp){
  if (isb){
    const short* src = ((const short*)W) + WOFF;
    for (int j=tid; j<288; j+=256){
      int r=j/6, k=(j%6)*8;
      *(bf16x8*)&BT[r*rp+k] = *(const bf16x8*)(src + j*8);
    }
  } else {
    for (int i=tid;i<2304;i+=256){ int r=i/48,k=i%48; BT[r*rp+k]=f2bs(ldx(W,WOFF+i,false)); }
  }
}

// ---------------- init (nodes + stat buckets only; edge init fused into k_edge d0) ----------------
__global__ void k_init_nodes(const void* __restrict__ x, const void* __restrict__ W0,
                             const void* __restrict__ b0, float* __restrict__ h,
                             float* __restrict__ stats, float* __restrict__ zpart,
                             const void* __restrict__ fl){
  const bool isb = dflag(fl);
  int gid = blockIdx.x*256 + threadIdx.x;
  if (gid < DD*12288) stats[gid] = 0.f;
  if (gid < 64) zpart[gid] = 0.f;
  if (gid < NN*UU){
    int n = gid/UU, c = gid%UU;
    float acc = ldx(b0,c,isb) + ldx(W0,c*2,isb)*ldx(x,n*2,isb) + ldx(W0,c*2+1,isb)*ldx(x,n*2+1,isb);
    h[gid] = siluf(acc);
  }
}

// ---------------- node GEMMs (MFMA, RPN=72 tiles -> ~41KB LDS, 3 blocks/CU) ----------------
__global__ __launch_bounds__(256) void k_node(
    float* __restrict__ h, float* __restrict__ h1,
    short* __restrict__ h24, short* __restrict__ h3b,
    const void* __restrict__ W1, const void* __restrict__ W2,
    const void* __restrict__ W3, const void* __restrict__ W4,
    const void* __restrict__ b1, const void* __restrict__ b2,
    const void* __restrict__ b3, const void* __restrict__ b4,
    const void* __restrict__ gv, const void* __restrict__ bv,
    const float* __restrict__ stats, int ctl, const void* __restrict__ fl)
{
  const bool isb = dflag(fl);
  const int d = ctl>>1, apply = ctl&1;
  const size_t WOFF = (size_t)d*UU*UU, BOFF = (size_t)d*UU;
  __shared__ alignas(16) short BT[4][48*RPN];
  __shared__ alignas(16) short AT[4][16*RPN];
  __shared__ float bL[4][UU];
  __shared__ float scV[96];
  __shared__ float sred[96];
  int tid = threadIdx.x, lane = tid&63, wid = tid>>6;
  const void* Ws[4] = {W1,W2,W3,W4};
  const void* bs[4] = {b1,b2,b3,b4};
  #pragma unroll
  for (int m=0;m<4;m++) stageW(BT[m], Ws[m], WOFF, isb, tid, RPN);
  for (int i=tid;i<4*768;i+=256){ int m=i/768, j=i%768; int r=j/16,k=48+(j%16); BT[m][r*RPN+k]=0; }
  for (int i=tid;i<4*256;i+=256){ int wv=i/256, j=i%256; int r=j/16,k=48+(j%16); AT[wv][r*RPN+k]=0; }
  if (tid<192) bL[tid/48][tid%48] = ldx(bs[tid/48],BOFF+(tid%48),isb);
  if (apply && tid<96){
    const float* sp = stats + (size_t)(d-1)*12288;   // v-branch buckets
    float s=0.f;
    for (int k2=0;k2<64;k2++) s += sp[k2*96+tid];
    sred[tid]=s;
  }
  __syncthreads();
  if (apply && tid<48){
    float mean = sred[tid]/(float)NN;
    float var = sred[48+tid]/(float)NN - mean*mean; if (var<0.f) var=0.f;
    float sc = ldx(gv,(size_t)(d-1)*48+tid,isb) * rsqrtf(var+EPSBN);
    scV[tid]=sc; scV[48+tid]=ldx(bv,(size_t)(d-1)*48+tid,isb) - mean*sc;
  }
  __syncthreads();

  int quad = lane>>4, lrow = lane&15;
  short* A = AT[wid];
  int gw = blockIdx.x*4+wid, gws = gridDim.x*4;
  const int NT = (NN+15)/16;
  for (int t=gw; t<NT; t+=gws){
    int nb = t*16;
    #pragma unroll
    for (int j=0;j<3;j++){
      int f = lane+64*j; int r=f/12, c4=f%12; int n=nb+r;
      short4 s4; s4.x=0;s4.y=0;s4.z=0;s4.w=0;
      if (n<NN){
        size_t gi = (size_t)n*48 + c4*4;
        float4 hv = *(const float4*)&h[gi];
        if (apply){
          float4 yv = *(const float4*)&h1[gi];
          int c0=c4*4;
          hv.x += siluf(scV[c0+0]*yv.x + scV[48+c0+0]);
          hv.y += siluf(scV[c0+1]*yv.y + scV[48+c0+1]);
          hv.z += siluf(scV[c0+2]*yv.z + scV[48+c0+2]);
          hv.w += siluf(scV[c0+3]*yv.w + scV[48+c0+3]);
          *(float4*)&h[gi] = hv;
        }
        s4.x=f2bs(hv.x); s4.y=f2bs(hv.y); s4.z=f2bs(hv.z); s4.w=f2bs(hv.w);
      }
      *(short4*)&A[r*RPN + c4*4] = s4;
    }
    LDSFENCE();
    bf16x8 a0 = *(const bf16x8*)&A[lrow*RPN + quad*8];
    bf16x8 a1 = *(const bf16x8*)&A[lrow*RPN + 32 + quad*8];
    #pragma unroll
    for (int m=0;m<4;m++){
      f32x4 ac0={0,0,0,0}, ac1={0,0,0,0}, ac2={0,0,0,0};
      bf16x8 bfr;
      bfr = *(const bf16x8*)&BT[m][(0+lrow)*RPN + quad*8];      ac0=__builtin_amdgcn_mfma_f32_16x16x32_bf16(a0,bfr,ac0,0,0,0);
      bfr = *(const bf16x8*)&BT[m][(0+lrow)*RPN + 32 + quad*8]; ac0=__builtin_amdgcn_mfma_f32_16x16x32_bf16(a1,bfr,ac0,0,0,0);
      bfr = *(const bf16x8*)&BT[m][(16+lrow)*RPN + quad*8];     ac1=__builtin_amdgcn_mfma_f32_16x16x32_bf16(a0,bfr,ac1,0,0,0);
      bfr = *(const bf16x8*)&BT[m][(16+lrow)*RPN + 32 + quad*8];ac1=__builtin_amdgcn_mfma_f32_16x16x32_bf16(a1,bfr,ac1,0,0,0);
      bfr = *(const bf16x8*)&BT[m][(32+lrow)*RPN + quad*8];     ac2=__builtin_amdgcn_mfma_f32_16x16x32_bf16(a0,bfr,ac2,0,0,0);
      bfr = *(const bf16x8*)&BT[m][(32+lrow)*RPN + 32 + quad*8];ac2=__builtin_amdgcn_mfma_f32_16x16x32_bf16(a1,bfr,ac2,0,0,0);
      #pragma unroll
      for (int nt=0;nt<3;nt++){
        int c = nt*16+lrow;
        f32x4 ac = (nt==0)?ac0:((nt==1)?ac1:ac2);
        float bv2 = bL[m][c];
        #pragma unroll
        for (int r=0;r<4;r++){
          int n = nb + quad*4 + r;
          if (n<NN){
            float v = ac[r] + bv2;
            if (m==0) h1[(size_t)n*48+c] = v;
            else if (m==1) h24[(size_t)n*96+c*2]   = f2hs(v);   // h2 even
            else if (m==2) h3b[(size_t)n*48+c]     = f2hs(v);
            else           h24[(size_t)n*96+c*2+1] = f2hs(v);   // h4 odd
          }
        }
      }
    }
  }
}

// ---------------- edge layer: 2 nodes/wave-iter; uniform-branch staging (clean d0 path) ----------------
__global__ __launch_bounds__(256,4) void k_edge(
    short* __restrict__ w, short* __restrict__ tmp,
    float* __restrict__ h1, const short* __restrict__ h24,
    const short* __restrict__ h3b,
    const int* __restrict__ dst,
    const void* __restrict__ We, const void* __restrict__ eb,
    const void* __restrict__ ge, const void* __restrict__ be,
    const void* __restrict__ ea, const void* __restrict__ eW0,
    const void* __restrict__ eb0,
    float* __restrict__ stats, int ctl, const void* __restrict__ fl)
{
  const bool isb = dflag(fl);
  const int d = ctl>>1, apply = ctl&1;
  const size_t WOFF = (size_t)d*UU*UU, BOFF = (size_t)d*UU;
  __shared__ alignas(16) short BT[48*RP];
  __shared__ alignas(16) short AT[4][32*RPA];   // 2 A-tiles per wave
  __shared__ float ebL[UU];
  __shared__ float scE[96];                     // apply: BN scale/shift; d0: eW0/eb0
  __shared__ float sred[96];
  __shared__ float sACC[4][192];
  int tid = threadIdx.x, lane = tid&63, wid = tid>>6;
  stageW(BT, We, WOFF, isb, tid, RP);
  for (int i=tid;i<768;i+=256){ int r=i/16,k=48+(i%16); BT[r*RP+k]=0; }
  for (int i=tid;i<4*512;i+=256){ int wv=i/512, j=i%512; int tile=j/256, jj=j%256;
    int r=jj/16, k=48+(jj%16); AT[wv][tile*16*RPA + r*RPA + k]=0; }
  if (tid<48) ebL[tid]=ldx(eb,BOFF+tid,isb);
  for (int i=tid;i<768;i+=256) ((float*)sACC)[i]=0.f;
  if (apply && tid<96){
    const float* sp = stats + (size_t)(d-1)*12288 + 6144;  // e-branch buckets
    float s=0.f;
    for (int k2=0;k2<64;k2++) s += sp[k2*96+tid];
    sred[tid]=s;
  }
  if (!apply && tid<96){   // layer 0: stage init weights into scE
    scE[tid] = (tid<48) ? ldx(eW0,tid,isb) : ldx(eb0,tid-48,isb);
  }
  __syncthreads();
  if (apply && tid<48){
    float mean = sred[tid]/(float)EE;
    float var = sred[48+tid]/(float)EE - mean*mean; if (var<0.f) var=0.f;
    float sc = ldx(ge,(size_t)(d-1)*48+tid,isb) * rsqrtf(var+EPSBN);
    scE[tid]=sc; scE[48+tid]=ldx(be,(size_t)(d-1)*48+tid,isb) - mean*sc;
  }
  __syncthreads();

  int quad = lane>>4, lrow = lane&15;
  short* A0 = AT[wid];
  short* A1 = AT[wid] + 16*RPA;
  float* myStats = stats + (size_t)d*12288;
  float accY[3]={0,0,0}, accY2[3]={0,0,0}, accT[3]={0,0,0}, accT2[3]={0,0,0};
  int gw = blockIdx.x*4+wid, gws = gridDim.x*4;
  const int NP = NN/2;   // 12500 node pairs
  for (int p=gw; p<NP; p+=gws){
    int n0 = p*2, n1 = n0+1;
    size_t b0 = (size_t)n0*768, b1 = (size_t)n1*768;
    int4 de0 = *(const int4*)&dst[n0*16 + quad*4];
    int4 de1 = *(const int4*)&dst[n1*16 + quad*4];

    // stage both nodes — apply is KERNEL-UNIFORM, so this branch is free;
    // each path keeps its optimal load scheduling (hoisted loads in apply;
    // no garbage w/tmp reads at d0).
    if (apply){
      #pragma unroll
      for (int j=0;j<3;j++){
        int idx = lane + 64*j;           // 0..191
        int u = idx/96, jj = idx%96;
        int r = jj/6, c0 = (jj%6)*8;
        size_t bn = u ? b1 : b0;
        short* Au = u ? A1 : A0;
        sx8 w8 = *(const sx8*)&w[bn + r*48 + c0];
        sx8 t8 = *(const sx8*)&tmp[bn + r*48 + c0];
        float f[8];
        #pragma unroll
        for (int q=0;q<8;q++) f[q] = hs2f(w8[q]) + siluf(scE[c0+q]*hs2f(t8[q]) + scE[48+c0+q]);
        sx8 ws8;
        #pragma unroll
        for (int q=0;q<8;q++) ws8[q] = f2hs(f[q]);
        *(sx8*)&w[bn + r*48 + c0] = ws8;
        sx8 a8;
        #pragma unroll
        for (int q=0;q<8;q++) a8[q] = f2bs(f[q]);
        *(sx8*)&Au[r*RPA + c0] = a8;
      }
    } else {
      #pragma unroll
      for (int j=0;j<3;j++){
        int idx = lane + 64*j;
        int u = idx/96, jj = idx%96;
        int r = jj/6, c0 = (jj%6)*8;
        size_t bn = u ? b1 : b0;
        short* Au = u ? A1 : A0;
        int n = u ? n1 : n0;
        float eav = ldx(ea, (size_t)n*16 + r, isb);
        float f[8];
        #pragma unroll
        for (int q=0;q<8;q++) f[q] = siluf(scE[c0+q]*eav + scE[48+c0+q]);
        sx8 ws8;
        #pragma unroll
        for (int q=0;q<8;q++) ws8[q] = f2hs(f[q]);
        *(sx8*)&w[bn + r*48 + c0] = ws8;
        sx8 a8;
        #pragma unroll
        for (int q=0;q<8;q++) a8[q] = f2bs(f[q]);
        *(sx8*)&Au[r*RPA + c0] = a8;
      }
    }
    LDSFENCE();
    bf16x8 a00 = *(const bf16x8*)&A0[lrow*RPA + quad*8];
    bf16x8 a01 = *(const bf16x8*)&A0[lrow*RPA + 32 + quad*8];
    bf16x8 a10 = *(const bf16x8*)&A1[lrow*RPA + quad*8];
    bf16x8 a11 = *(const bf16x8*)&A1[lrow*RPA + 32 + quad*8];
    f32x4 acc[2][3];
    #pragma unroll
    for (int u=0;u<2;u++)
      #pragma unroll
      for (int nt=0;nt<3;nt++) acc[u][nt] = (f32x4){0,0,0,0};
    #pragma unroll
    for (int nt=0;nt<3;nt++){
      bf16x8 bf0 = *(const bf16x8*)&BT[(nt*16+lrow)*RP + quad*8];
      bf16x8 bf1 = *(const bf16x8*)&BT[(nt*16+lrow)*RP + 32 + quad*8];
      acc[0][nt]=__builtin_amdgcn_mfma_f32_16x16x32_bf16(a00,bf0,acc[0][nt],0,0,0);
      acc[0][nt]=__builtin_amdgcn_mfma_f32_16x16x32_bf16(a01,bf1,acc[0][nt],0,0,0);
      acc[1][nt]=__builtin_amdgcn_mfma_f32_16x16x32_bf16(a10,bf0,acc[1][nt],0,0,0);
      acc[1][nt]=__builtin_amdgcn_mfma_f32_16x16x32_bf16(a11,bf1,acc[1][nt],0,0,0);
    }
    // epilogue per node
    #pragma unroll
    for (int u=0;u<2;u++){
      int n = n0+u;
      size_t bn = u? b1 : b0;
      short* Au = u? A1 : A0;
      int dei[4];
      if (u==0){ dei[0]=de0.x; dei[1]=de0.y; dei[2]=de0.z; dei[3]=de0.w; }
      else     { dei[0]=de1.x; dei[1]=de1.y; dei[2]=de1.z; dei[3]=de1.w; }
      #pragma unroll
      for (int nt=0;nt<3;nt++){
        int c = nt*16+lrow;
        f32x4 ac = acc[u][nt];
        float bv = ebL[c];
        float h3v = hs2f(h3b[(size_t)n*48+c]);
        float pT=0.f, pT2=0.f, pM=0.f;
        #pragma unroll
        for (int r=0;r<4;r++){
          int e = quad*4+r;
          union { unsigned uu; short2 ss; } gpair;
          gpair.uu = *(const unsigned*)&h24[(size_t)dei[r]*96 + c*2];
          float h2v = hs2f(gpair.ss.x);
          float h4v = hs2f(gpair.ss.y);
          float t = ac[r] + bv + h3v + h4v;
          tmp[bn + e*48 + c] = f2hs(t);
          pT += t; pT2 += t*t;
          float gate = bs2f(Au[e*RPA+c]);
          pM += h2v * sigm(gate);
        }
        pT  += __shfl_xor(pT,16);  pT  += __shfl_xor(pT,32);
        pT2 += __shfl_xor(pT2,16); pT2 += __shfl_xor(pT2,32);
        pM  += __shfl_xor(pM,16);  pM  += __shfl_xor(pM,32);
        accT[nt] += pT; accT2[nt] += pT2;
        if (u==0){
          if (lane<16){
            float yv = h1[(size_t)n*48+c] + pM*(1.f/16.f);
            h1[(size_t)n*48+c] = yv;
            accY[nt] += yv; accY2[nt] += yv*yv;
          }
        } else {
          if (lane>=16 && lane<32){
            float yv = h1[(size_t)n*48+c] + pM*(1.f/16.f);
            h1[(size_t)n*48+c] = yv;
            accY[nt] += yv; accY2[nt] += yv*yv;
          }
        }
      }
    }
  }
  #pragma unroll
  for (int nt=0;nt<3;nt++){
    accY[nt]  += __shfl_xor(accY[nt],16);
    accY2[nt] += __shfl_xor(accY2[nt],16);
  }
  if (lane<16){
    #pragma unroll
    for (int nt=0;nt<3;nt++){
      int c = nt*16+lane;
      sACC[wid][c]      = accY[nt];
      sACC[wid][48+c]   = accY2[nt];
      sACC[wid][96+c]   = accT[nt];
      sACC[wid][144+c]  = accT2[nt];
    }
  }
  __syncthreads();
  if (tid<192){
    float s = sACC[0][tid]+sACC[1][tid]+sACC[2][tid]+sACC[3][tid];
    int bk = (blockIdx.x&63)*96;
    if (tid<96) atomicAdd(&myStats[bk+tid], s);
    else        atomicAdd(&myStats[6144+bk+(tid-96)], s);
  }
}

// ---------------- head 1: final e-BN + p1 GEMM + z GEMM ----------------
__global__ __launch_bounds__(256) void k_head1(
    const short* __restrict__ w, short* __restrict__ tmp,
    const void* __restrict__ pW0, const void* __restrict__ pb0,
    const void* __restrict__ zW0, const void* __restrict__ zb0,
    const void* __restrict__ zW1,
    const void* __restrict__ ge, const void* __restrict__ be,
    const float* __restrict__ stats, float* __restrict__ zpart,
    const void* __restrict__ fl)
{
  const bool isb = dflag(fl);
  __shared__ alignas(16) short BT0[48*RP];
  __shared__ alignas(16) short BT1[48*RP];
  __shared__ alignas(16) short AT[4][16*RP];
  __shared__ float pb0L[UU], zb0L[UU], zW1L[UU];
  __shared__ float scE[96];
  __shared__ float sred[96];
  __shared__ float zS[4];
  int tid = threadIdx.x, lane = tid&63, wid = tid>>6;
  stageW(BT0, pW0, 0, isb, tid, RP);
  stageW(BT1, zW0, 0, isb, tid, RP);
  for (int i=tid;i<768;i+=256){ int r=i/16,k=48+(i%16); BT0[r*RP+k]=0; BT1[r*RP+k]=0; }
  for (int i=tid;i<4*256;i+=256){ int wv=i/256, j=i%256; int r=j/16,k=48+(j%16); AT[wv][r*RP+k]=0; }
  if (tid<48){ pb0L[tid]=ldx(pb0,tid,isb); zb0L[tid]=ldx(zb0,tid,isb); zW1L[tid]=ldx(zW1,tid,isb); }
  if (tid<96){
    const float* sp = stats + (size_t)(DD-1)*12288 + 6144;
    float s=0.f;
    for (int k2=0;k2<64;k2++) s += sp[k2*96+tid];
    sred[tid]=s;
  }
  __syncthreads();
  if (tid<48){
    float mean = sred[tid]/(float)EE;
    float var = sred[48+tid]/(float)EE - mean*mean; if (var<0.f) var=0.f;
    float sc = ldx(ge,(size_t)(DD-1)*48+tid,isb) * rsqrtf(var+EPSBN);
    scE[tid]=sc; scE[48+tid]=ldx(be,(size_t)(DD-1)*48+tid,isb) - mean*sc;
  }
  __syncthreads();

  int quad = lane>>4, lrow = lane&15;
  short* A = AT[wid];
  float zacc = 0.f;
  int gw = blockIdx.x*4+wid, gws = gridDim.x*4;
  for (int n=gw; n<NN; n+=gws){
    size_t basef = (size_t)n*768;
    #pragma unroll
    for (int j=0;j<2;j++){
      int idx = lane + 64*j;
      if (idx < 96){
        int r = idx/6, c0 = (idx%6)*8;
        sx8 w8 = *(const sx8*)&w[basef + r*48 + c0];
        sx8 t8 = *(const sx8*)&tmp[basef + r*48 + c0];
        sx8 a8;
        #pragma unroll
        for (int q=0;q<8;q++){
          float f = hs2f(w8[q]) + siluf(scE[c0+q]*hs2f(t8[q]) + scE[48+c0+q]);
          a8[q] = f2bs(f);
        }
        *(sx8*)&A[r*RP + c0] = a8;
      }
    }
    LDSFENCE();
    bf16x8 a0 = *(const bf16x8*)&A[lrow*RP + quad*8];
    bf16x8 a1 = *(const bf16x8*)&A[lrow*RP + 32 + quad*8];
    f32x4 p0={0,0,0,0}, p1={0,0,0,0}, p2={0,0,0,0};
    f32x4 z0={0,0,0,0}, z1={0,0,0,0}, z2={0,0,0,0};
    bf16x8 bfr;
    bfr=*(const bf16x8*)&BT0[(0+lrow)*RP+quad*8];       p0=__builtin_amdgcn_mfma_f32_16x16x32_bf16(a0,bfr,p0,0,0,0);
    bfr=*(const bf16x8*)&BT0[(0+lrow)*RP+32+quad*8];    p0=__builtin_amdgcn_mfma_f32_16x16x32_bf16(a1,bfr,p0,0,0,0);
    bfr=*(const bf16x8*)&BT0[(16+lrow)*RP+quad*8];      p1=__builtin_amdgcn_mfma_f32_16x16x32_bf16(a0,bfr,p1,0,0,0);
    bfr=*(const bf16x8*)&BT0[(16+lrow)*RP+32+quad*8];   p1=__builtin_amdgcn_mfma_f32_16x16x32_bf16(a1,bfr,p1,0,0,0);
    bfr=*(const bf16x8*)&BT0[(32+lrow)*RP+quad*8];      p2=__builtin_amdgcn_mfma_f32_16x16x32_bf16(a0,bfr,p2,0,0,0);
    bfr=*(const bf16x8*)&BT0[(32+lrow)*RP+32+quad*8];   p2=__builtin_amdgcn_mfma_f32_16x16x32_bf16(a1,bfr,p2,0,0,0);
    bfr=*(const bf16x8*)&BT1[(0+lrow)*RP+quad*8];       z0=__builtin_amdgcn_mfma_f32_16x16x32_bf16(a0,bfr,z0,0,0,0);
    bfr=*(const bf16x8*)&BT1[(0+lrow)*RP+32+quad*8];    z0=__builtin_amdgcn_mfma_f32_16x16x32_bf16(a1,bfr,z0,0,0,0);
    bfr=*(const bf16x8*)&BT1[(16+lrow)*RP+quad*8];      z1=__builtin_amdgcn_mfma_f32_16x16x32_bf16(a0,bfr,z1,0,0,0);
    bfr=*(const bf16x8*)&BT1[(16+lrow)*RP+32+quad*8];   z1=__builtin_amdgcn_mfma_f32_16x16x32_bf16(a1,bfr,z1,0,0,0);
    bfr=*(const bf16x8*)&BT1[(32+lrow)*RP+quad*8];      z2=__builtin_amdgcn_mfma_f32_16x16x32_bf16(a0,bfr,z2,0,0,0);
    bfr=*(const bf16x8*)&BT1[(32+lrow)*RP+32+quad*8];   z2=__builtin_amdgcn_mfma_f32_16x16x32_bf16(a1,bfr,z2,0,0,0);
    #pragma unroll
    for (int nt=0;nt<3;nt++){
      int c = nt*16+lrow;
      f32x4 pp = (nt==0)?p0:((nt==1)?p1:p2);
      f32x4 zz = (nt==0)?z0:((nt==1)?z1:z2);
      float pb = pb0L[c], zb = zb0L[c], zw = zW1L[c];
      #pragma unroll
      for (int r=0;r<4;r++){
        int e = quad*4+r;
        tmp[basef + e*48 + c] = f2bs(siluf(pp[r] + pb));  // p1 bf16 (head2 MFMA A operand)
        float zr = zz[r] + zb;
        zacc += zw * (zr > 0.f ? zr : 0.f);
      }
    }
  }
  zacc += __shfl_xor(zacc,1); zacc += __shfl_xor(zacc,2); zacc += __shfl_xor(zacc,4);
  zacc += __shfl_xor(zacc,8); zacc += __shfl_xor(zacc,16); zacc += __shfl_xor(zacc,32);
  if (lane==0) zS[wid]=zacc;
  __syncthreads();
  if (tid==0) atomicAdd(&zpart[blockIdx.x&63], zS[0]+zS[1]+zS[2]+zS[3]);
}

// ---------------- head 2: p2 GEMM + scalar head + group softmax ----------------
__global__ __launch_bounds__(256) void k_head2(
    const short* __restrict__ tmp,
    const void* __restrict__ pW1, const void* __restrict__ pb1,
    const void* __restrict__ pW2,
    void* __restrict__ out, const void* __restrict__ fl)
{
  const bool isb = dflag(fl);
  __shared__ alignas(16) short BT[48*RP];
  __shared__ alignas(16) short AT[4][16*RP];
  __shared__ float pb1L[UU], pW2L[UU];
  int tid = threadIdx.x, lane = tid&63, wid = tid>>6;
  stageW(BT, pW1, 0, isb, tid, RP);
  for (int i=tid;i<768;i+=256){ int r=i/16,k=48+(i%16); BT[r*RP+k]=0; }
  for (int i=tid;i<4*256;i+=256){ int wv=i/256, j=i%256; int r=j/16,k=48+(j%16); AT[wv][r*RP+k]=0; }
  if (tid<48){ pb1L[tid]=ldx(pb1,tid,isb); pW2L[tid]=ldx(pW2,tid,isb); }
  __syncthreads();

  int quad = lane>>4, lrow = lane&15;
  short* A = AT[wid];
  int gw = blockIdx.x*4+wid, gws = gridDim.x*4;
  for (int n=gw; n<NN; n+=gws){
    size_t basef = (size_t)n*768;
    #pragma unroll
    for (int j=0;j<2;j++){
      int idx = lane + 64*j;
      if (idx < 96){
        int r = idx/6, c8 = idx%6;
        *(bf16x8*)&A[r*RP + c8*8] = *(const bf16x8*)&tmp[basef + r*48 + c8*8];
      }
    }
    LDSFENCE();
    bf16x8 a0 = *(const bf16x8*)&A[lrow*RP + quad*8];
    bf16x8 a1 = *(const bf16x8*)&A[lrow*RP + 32 + quad*8];
    f32x4 q0={0,0,0,0}, q1={0,0,0,0}, q2={0,0,0,0};
    bf16x8 bfr;
    bfr=*(const bf16x8*)&BT[(0+lrow)*RP+quad*8];       q0=__builtin_amdgcn_mfma_f32_16x16x32_bf16(a0,bfr,q0,0,0,0);
    bfr=*(const bf16x8*)&BT[(0+lrow)*RP+32+quad*8];    q0=__builtin_amdgcn_mfma_f32_16x16x32_bf16(a1,bfr,q0,0,0,0);
    bfr=*(const bf16x8*)&BT[(16+lrow)*RP+quad*8];      q1=__builtin_amdgcn_mfma_f32_16x16x32_bf16(a0,bfr,q1,0,0,0);
    bfr=*(const bf16x8*)&BT[(16+lrow)*RP+32+quad*8];   q1=__builtin_amdgcn_mfma_f32_16x16x32_bf16(a1,bfr,q1,0,0,0);
    bfr=*(const bf16x8*)&BT[(32+lrow)*RP+quad*8];      q2=__builtin_amdgcn_mfma_f32_16x16x32_bf16(a0,bfr,q2,0,0,0);
    bfr=*(const bf16x8*)&BT[(32+lrow)*RP+32+quad*8];   q2=__builtin_amdgcn_mfma_f32_16x16x32_bf16(a1,bfr,q2,0,0,0);
    float pp[4] = {0.f,0.f,0.f,0.f};
    #pragma unroll
    for (int nt=0;nt<3;nt++){
      int c = nt*16+lrow;
      f32x4 qq = (nt==0)?q0:((nt==1)?q1:q2);
      float pb = pb1L[c], pw = pW2L[c];
      #pragma unroll
      for (int r=0;r<4;r++) pp[r] += pw * siluf(qq[r] + pb);
    }
    #pragma unroll
    for (int r=0;r<4;r++){
      pp[r] += __shfl_xor(pp[r],1); pp[r] += __shfl_xor(pp[r],2);
      pp[r] += __shfl_xor(pp[r],4); pp[r] += __shfl_xor(pp[r],8);
    }
    float mx = fmaxf(fmaxf(pp[0],pp[1]), fmaxf(pp[2],pp[3]));
    mx = fmaxf(mx, __shfl_xor(mx,16)); mx = fmaxf(mx, __shfl_xor(mx,32));
    float ex[4]; float se = 0.f;
    #pragma unroll
    for (int r=0;r<4;r++){ ex[r] = __expf(pp[r]-mx); se += ex[r]; }
    se += __shfl_xor(se,16); se += __shfl_xor(se,32);
    float inv = 1.f/se;
    if (lrow==0){
      #pragma unroll
      for (int r=0;r<4;r++) stout(out, (size_t)n*16 + quad*4 + r, ex[r]*inv, isb);
    }
  }
}

__global__ void k_final(const float* __restrict__ zpart, const void* __restrict__ zb1,
                        void* __restrict__ out, const void* __restrict__ fl){
  const bool isb = dflag(fl);
  int tid=threadIdx.x;
  float s = (tid<64) ? zpart[tid] : 0.f;
  s += __shfl_xor(s,1); s += __shfl_xor(s,2); s += __shfl_xor(s,4);
  s += __shfl_xor(s,8); s += __shfl_xor(s,16); s += __shfl_xor(s,32);
  if (tid==0) stout(out, EE, s/(float)EE + ldx(zb1,0,isb), isb);
}

extern "C" void kernel_launch(void* const* d_in, const int* in_sizes, int n_in,
                              void* d_out, int out_size, void* d_ws, size_t ws_size,
                              hipStream_t stream){
  (void)in_sizes; (void)n_in; (void)out_size; (void)ws_size;
  const void* x=d_in[0]; const void* ea=d_in[1];
  const int* ei=(const int*)d_in[2];
  const void* vW0=d_in[3]; const void* vb0=d_in[4];
  const void* vW1=d_in[5]; const void* vW2=d_in[6]; const void* vW3=d_in[7]; const void* vW4=d_in[8];
  const void* vb1=d_in[9]; const void* vb2=d_in[10]; const void* vb3=d_in[11]; const void* vb4=d_in[12];
  const void* vbng=d_in[13]; const void* vbnb=d_in[14];
  const void* eW0=d_in[15]; const void* eb0=d_in[16];
  const void* eW=d_in[17]; const void* ebv=d_in[18];
  const void* ebng=d_in[19]; const void* ebnb=d_in[20];
  const void* pW0=d_in[21]; const void* pb0=d_in[22];
  const void* pW1=d_in[23]; const void* pb1=d_in[24];
  const void* pW2=d_in[25]; const void* pb2=d_in[26]; (void)pb2; // cancels in softmax
  const void* zW0=d_in[27]; const void* zb0=d_in[28];
  const void* zW1=d_in[29]; const void* zb1=d_in[30];
  const int* dst = ei + EE;
  const void* fl = vbng;

  float* h   = (float*)d_ws;                       // [N,48] f32
  float* h1  = h  + (size_t)NN*UU;                 // [N,48] f32
  short* h24 = (short*)(h1 + (size_t)NN*UU);       // [N,96] f16 interleaved h2/h4
  short* h3b = h24 + (size_t)NN*96;                // [N,48] f16
  short* w   = h3b + (size_t)NN*UU;                // [E,48] f16 (residual trunk)
  short* tmp = w + (size_t)EE*UU;                  // [E,48] f16 t (head1 stores bf16 p1)
  float* stats = (float*)(tmp + (size_t)EE*UU);    // 12 layers x 12288
  float* zpart = stats + DD*12288;

  k_init_nodes<<<(NN*UU+255)/256,256,0,stream>>>(x,vW0,vb0,h,stats,zpart,fl);
  for (int d=0; d<DD; d++){
    int ctl = (d<<1) | (d>0 ? 1 : 0);
    k_node<<<768,256,0,stream>>>(h,h1,h24,h3b,
        vW1,vW2,vW3,vW4,vb1,vb2,vb3,vb4,vbng,vbnb,stats,ctl,fl);
    k_edge<<<1280,256,0,stream>>>(w,tmp,h1,h24,h3b,dst,eW,ebv,ebng,ebnb,
        ea,eW0,eb0,stats,ctl,fl);
  }
  k_head1<<<1024,256,0,stream>>>(w,tmp,pW0,pb0,zW0,zb0,zW1,ebng,ebnb,stats,zpart,fl);
  k_head2<<<1024,256,0,stream>>>(tmp,pW1,pb1,pW2,d_out,fl);
  k_final<<<1,64,0,stream>>>(zpart,zb1,d_out,fl);
}

// Round 17
// 1238.931 us; speedup vs baseline: 1.0978x; 1.0978x over previous
//
#include <hip/hip_runtime.h>
#include <hip/hip_bf16.h>
#include <hip/hip_fp16.h>

#define NN 25000
#define KK 16
#define EE 400000
#define DD 12
#define UU 48
#define EPSBN 1e-5f
#define RP 88    // LDS row stride for 48x48 B-tiles (halfwords)
#define RPA 72   // LDS row stride for A-tiles (K padded to 64)

using bf16 = __hip_bfloat16;
typedef short bf16x8 __attribute__((ext_vector_type(8)));
typedef short sx8 __attribute__((ext_vector_type(8)));
typedef float f32x4 __attribute__((ext_vector_type(4)));

__device__ __forceinline__ float b2f(bf16 v){ return __bfloat162float(v); }
__device__ __forceinline__ float sigm(float x){ return 1.f/(1.f+__expf(-x)); }
__device__ __forceinline__ float siluf(float x){ return x/(1.f+__expf(-x)); }
__device__ __forceinline__ short f2bs(float f){ bf16 h=__float2bfloat16(f); return *(short*)&h; }
__device__ __forceinline__ float bs2f(short s){ bf16 h; *(short*)&h = s; return __bfloat162float(h); }
__device__ __forceinline__ short f2hs(float f){ __half h=__float2half(f); return *(short*)&h; }
__device__ __forceinline__ float hs2f(short s){ __half h; *(short*)&h = s; return __half2float(h); }

__device__ __forceinline__ float ldx(const void* p, size_t i, bool isb){
  return isb ? b2f(((const bf16*)p)[i]) : ((const float*)p)[i];
}
__device__ __forceinline__ void stout(void* p, size_t i, float v, bool isb){
  if (isb) ((bf16*)p)[i] = __float2bfloat16(v);
  else     ((float*)p)[i] = v;
}
__device__ __forceinline__ bool dflag(const void* vbng){
  return *((const unsigned*)vbng) == 0x3F803F80u;
}
#define LDSFENCE() asm volatile("s_waitcnt lgkmcnt(0)" ::: "memory")

__device__ __forceinline__ void stageW(short* BT, const void* W, size_t WOFF, bool isb, int tid){
  if (isb){
    const short* src = ((const short*)W) + WOFF;
    for (int j=tid; j<288; j+=256){
      int r=j/6, k=(j%6)*8;
      *(bf16x8*)&BT[r*RP+k] = *(const bf16x8*)(src + j*8);
    }
  } else {
    for (int i=tid;i<2304;i+=256){ int r=i/48,k=i%48; BT[r*RP+k]=f2bs(ldx(W,WOFF+i,false)); }
  }
}

// ---------------- init ----------------
__global__ void k_init_nodes(const void* __restrict__ x, const void* __restrict__ W0,
                             const void* __restrict__ b0, float* __restrict__ h,
                             float* __restrict__ stats, float* __restrict__ zpart,
                             const void* __restrict__ fl){
  const bool isb = dflag(fl);
  int gid = blockIdx.x*256 + threadIdx.x;
  if (gid < DD*12288) stats[gid] = 0.f;
  if (gid < 64) zpart[gid] = 0.f;
  if (gid < NN*UU){
    int n = gid/UU, c = gid%UU;
    float acc = ldx(b0,c,isb) + ldx(W0,c*2,isb)*ldx(x,n*2,isb) + ldx(W0,c*2+1,isb)*ldx(x,n*2+1,isb);
    h[gid] = siluf(acc);
  }
}

__global__ void k_init_edges(const void* __restrict__ ea, const void* __restrict__ W0,
                             const void* __restrict__ b0, short* __restrict__ w,
                             const void* __restrict__ fl){
  const bool isb = dflag(fl);
  int gid = blockIdx.x*256 + threadIdx.x;
  if (gid < EE*UU){
    int e = gid/UU, c = gid%UU;
    float acc = ldx(b0,c,isb) + ldx(W0,c,isb)*ldx(ea,e,isb);
    w[gid] = f2hs(siluf(acc));
  }
}

// ---------------- node GEMMs (MFMA, persistent, inline BN-stats reduce) ----------------
// h2/h4 write interleaved into h24[N,96]: even=h2, odd=h4
__global__ __launch_bounds__(256) void k_node(
    float* __restrict__ h, float* __restrict__ h1,
    short* __restrict__ h24, short* __restrict__ h3b,
    const void* __restrict__ W1, const void* __restrict__ W2,
    const void* __restrict__ W3, const void* __restrict__ W4,
    const void* __restrict__ b1, const void* __restrict__ b2,
    const void* __restrict__ b3, const void* __restrict__ b4,
    const void* __restrict__ gv, const void* __restrict__ bv,
    const float* __restrict__ stats, int ctl, const void* __restrict__ fl)
{
  const bool isb = dflag(fl);
  const int d = ctl>>1, apply = ctl&1;
  const size_t WOFF = (size_t)d*UU*UU, BOFF = (size_t)d*UU;
  __shared__ alignas(16) short BT[4][48*RP];
  __shared__ alignas(16) short AT[4][16*RP];
  __shared__ float bL[4][UU];
  __shared__ float scV[96];
  __shared__ float sred[96];
  int tid = threadIdx.x, lane = tid&63, wid = tid>>6;
  const void* Ws[4] = {W1,W2,W3,W4};
  const void* bs[4] = {b1,b2,b3,b4};
  #pragma unroll
  for (int m=0;m<4;m++) stageW(BT[m], Ws[m], WOFF, isb, tid);
  for (int i=tid;i<4*768;i+=256){ int m=i/768, j=i%768; int r=j/16,k=48+(j%16); BT[m][r*RP+k]=0; }
  for (int i=tid;i<4*256;i+=256){ int wv=i/256, j=i%256; int r=j/16,k=48+(j%16); AT[wv][r*RP+k]=0; }
  if (tid<192) bL[tid/48][tid%48] = ldx(bs[tid/48],BOFF+(tid%48),isb);
  if (apply && tid<96){
    const float* sp = stats + (size_t)(d-1)*12288;   // v-branch buckets
    float s=0.f;
    for (int k2=0;k2<64;k2++) s += sp[k2*96+tid];
    sred[tid]=s;
  }
  __syncthreads();
  if (apply && tid<48){
    float mean = sred[tid]/(float)NN;
    float var = sred[48+tid]/(float)NN - mean*mean; if (var<0.f) var=0.f;
    float sc = ldx(gv,(size_t)(d-1)*48+tid,isb) * rsqrtf(var+EPSBN);
    scV[tid]=sc; scV[48+tid]=ldx(bv,(size_t)(d-1)*48+tid,isb) - mean*sc;
  }
  __syncthreads();

  int quad = lane>>4, lrow = lane&15;
  short* A = AT[wid];
  int gw = blockIdx.x*4+wid, gws = gridDim.x*4;
  const int NT = (NN+15)/16;
  for (int t=gw; t<NT; t+=gws){
    int nb = t*16;
    #pragma unroll
    for (int j=0;j<3;j++){
      int f = lane+64*j; int r=f/12, c4=f%12; int n=nb+r;
      short4 s4; s4.x=0;s4.y=0;s4.z=0;s4.w=0;
      if (n<NN){
        size_t gi = (size_t)n*48 + c4*4;
        float4 hv = *(const float4*)&h[gi];
        if (apply){
          float4 yv = *(const float4*)&h1[gi];
          int c0=c4*4;
          hv.x += siluf(scV[c0+0]*yv.x + scV[48+c0+0]);
          hv.y += siluf(scV[c0+1]*yv.y + scV[48+c0+1]);
          hv.z += siluf(scV[c0+2]*yv.z + scV[48+c0+2]);
          hv.w += siluf(scV[c0+3]*yv.w + scV[48+c0+3]);
          *(float4*)&h[gi] = hv;
        }
        s4.x=f2bs(hv.x); s4.y=f2bs(hv.y); s4.z=f2bs(hv.z); s4.w=f2bs(hv.w);
      }
      *(short4*)&A[r*RP + c4*4] = s4;
    }
    LDSFENCE();
    bf16x8 a0 = *(const bf16x8*)&A[lrow*RP + quad*8];
    bf16x8 a1 = *(const bf16x8*)&A[lrow*RP + 32 + quad*8];
    #pragma unroll
    for (int m=0;m<4;m++){
      f32x4 ac0={0,0,0,0}, ac1={0,0,0,0}, ac2={0,0,0,0};
      bf16x8 bfr;
      bfr = *(const bf16x8*)&BT[m][(0+lrow)*RP + quad*8];      ac0=__builtin_amdgcn_mfma_f32_16x16x32_bf16(a0,bfr,ac0,0,0,0);
      bfr = *(const bf16x8*)&BT[m][(0+lrow)*RP + 32 + quad*8]; ac0=__builtin_amdgcn_mfma_f32_16x16x32_bf16(a1,bfr,ac0,0,0,0);
      bfr = *(const bf16x8*)&BT[m][(16+lrow)*RP + quad*8];     ac1=__builtin_amdgcn_mfma_f32_16x16x32_bf16(a0,bfr,ac1,0,0,0);
      bfr = *(const bf16x8*)&BT[m][(16+lrow)*RP + 32 + quad*8];ac1=__builtin_amdgcn_mfma_f32_16x16x32_bf16(a1,bfr,ac1,0,0,0);
      bfr = *(const bf16x8*)&BT[m][(32+lrow)*RP + quad*8];     ac2=__builtin_amdgcn_mfma_f32_16x16x32_bf16(a0,bfr,ac2,0,0,0);
      bfr = *(const bf16x8*)&BT[m][(32+lrow)*RP + 32 + quad*8];ac2=__builtin_amdgcn_mfma_f32_16x16x32_bf16(a1,bfr,ac2,0,0,0);
      #pragma unroll
      for (int nt=0;nt<3;nt++){
        int c = nt*16+lrow;
        f32x4 ac = (nt==0)?ac0:((nt==1)?ac1:ac2);
        float bv2 = bL[m][c];
        #pragma unroll
        for (int r=0;r<4;r++){
          int n = nb + quad*4 + r;
          if (n<NN){
            float v = ac[r] + bv2;
            if (m==0) h1[(size_t)n*48+c] = v;
            else if (m==1) h24[(size_t)n*96+c*2]   = f2hs(v);   // h2 even
            else if (m==2) h3b[(size_t)n*48+c]     = f2hs(v);
            else           h24[(size_t)n*96+c*2+1] = f2hs(v);   // h4 odd
          }
        }
      }
    }
  }
}

// ---------------- edge layer: 2 nodes/wave-iter, f16 w, interleaved h24 gathers ----------------
// launch_bounds (256,4): VGPR cap 128 — (256,5) forced 48 VGPRs -> scratch spills (R12).
__global__ __launch_bounds__(256,4) void k_edge(
    short* __restrict__ w, short* __restrict__ tmp,
    float* __restrict__ h1, const short* __restrict__ h24,
    const short* __restrict__ h3b,
    const int* __restrict__ dst,
    const void* __restrict__ We, const void* __restrict__ eb,
    const void* __restrict__ ge, const void* __restrict__ be,
    float* __restrict__ stats, int ctl, const void* __restrict__ fl)
{
  const bool isb = dflag(fl);
  const int d = ctl>>1, apply = ctl&1;
  const size_t WOFF = (size_t)d*UU*UU, BOFF = (size_t)d*UU;
  __shared__ alignas(16) short BT[48*RP];
  __shared__ alignas(16) short AT[4][32*RPA];   // 2 A-tiles per wave, RPA stride
  __shared__ float ebL[UU];
  __shared__ float scE[96];
  __shared__ float sred[96];
  __shared__ float sACC[4][192];
  int tid = threadIdx.x, lane = tid&63, wid = tid>>6;
  stageW(BT, We, WOFF, isb, tid);
  for (int i=tid;i<768;i+=256){ int r=i/16,k=48+(i%16); BT[r*RP+k]=0; }
  for (int i=tid;i<4*512;i+=256){ int wv=i/512, j=i%512; int tile=j/256, jj=j%256;
    int r=jj/16, k=48+(jj%16); AT[wv][tile*16*RPA + r*RPA + k]=0; }
  if (tid<48) ebL[tid]=ldx(eb,BOFF+tid,isb);
  for (int i=tid;i<768;i+=256) ((float*)sACC)[i]=0.f;
  if (apply && tid<96){
    const float* sp = stats + (size_t)(d-1)*12288 + 6144;  // e-branch buckets
    float s=0.f;
    for (int k2=0;k2<64;k2++) s += sp[k2*96+tid];
    sred[tid]=s;
  }
  __syncthreads();
  if (apply && tid<48){
    float mean = sred[tid]/(float)EE;
    float var = sred[48+tid]/(float)EE - mean*mean; if (var<0.f) var=0.f;
    float sc = ldx(ge,(size_t)(d-1)*48+tid,isb) * rsqrtf(var+EPSBN);
    scE[tid]=sc; scE[48+tid]=ldx(be,(size_t)(d-1)*48+tid,isb) - mean*sc;
  }
  __syncthreads();

  int quad = lane>>4, lrow = lane&15;
  short* A0 = AT[wid];
  short* A1 = AT[wid] + 16*RPA;
  float* myStats = stats + (size_t)d*12288;
  float accY[3]={0,0,0}, accY2[3]={0,0,0}, accT[3]={0,0,0}, accT2[3]={0,0,0};
  int gw = blockIdx.x*4+wid, gws = gridDim.x*4;
  const int NP = NN/2;   // 12500 node pairs
  for (int p=gw; p<NP; p+=gws){
    int n0 = p*2, n1 = n0+1;
    size_t b0 = (size_t)n0*768, b1 = (size_t)n1*768;
    int4 de0 = *(const int4*)&dst[n0*16 + quad*4];
    int4 de1 = *(const int4*)&dst[n1*16 + quad*4];

    // stage both nodes: 16B f16 chunks
    #pragma unroll
    for (int j=0;j<3;j++){
      int idx = lane + 64*j;           // 0..191
      int u = idx/96, jj = idx%96;
      int r = jj/6, c0 = (jj%6)*8;
      size_t bn = u ? b1 : b0;
      short* Au = u ? A1 : A0;
      sx8 w8 = *(const sx8*)&w[bn + r*48 + c0];
      float f[8];
      #pragma unroll
      for (int q=0;q<8;q++) f[q] = hs2f(w8[q]);
      if (apply){
        sx8 t8 = *(const sx8*)&tmp[bn + r*48 + c0];
        #pragma unroll
        for (int q=0;q<8;q++) f[q] += siluf(scE[c0+q]*hs2f(t8[q]) + scE[48+c0+q]);
        sx8 ws8;
        #pragma unroll
        for (int q=0;q<8;q++) ws8[q] = f2hs(f[q]);
        *(sx8*)&w[bn + r*48 + c0] = ws8;
      }
      sx8 a8;
      #pragma unroll
      for (int q=0;q<8;q++) a8[q] = f2bs(f[q]);
      *(sx8*)&Au[r*RPA + c0] = a8;
    }
    LDSFENCE();
    bf16x8 a00 = *(const bf16x8*)&A0[lrow*RPA + quad*8];
    bf16x8 a01 = *(const bf16x8*)&A0[lrow*RPA + 32 + quad*8];
    bf16x8 a10 = *(const bf16x8*)&A1[lrow*RPA + quad*8];
    bf16x8 a11 = *(const bf16x8*)&A1[lrow*RPA + 32 + quad*8];
    f32x4 acc[2][3];
    #pragma unroll
    for (int u=0;u<2;u++)
      #pragma unroll
      for (int nt=0;nt<3;nt++) acc[u][nt] = (f32x4){0,0,0,0};
    #pragma unroll
    for (int nt=0;nt<3;nt++){
      bf16x8 bf0 = *(const bf16x8*)&BT[(nt*16+lrow)*RP + quad*8];
      bf16x8 bf1 = *(const bf16x8*)&BT[(nt*16+lrow)*RP + 32 + quad*8];
      acc[0][nt]=__builtin_amdgcn_mfma_f32_16x16x32_bf16(a00,bf0,acc[0][nt],0,0,0);
      acc[0][nt]=__builtin_amdgcn_mfma_f32_16x16x32_bf16(a01,bf1,acc[0][nt],0,0,0);
      acc[1][nt]=__builtin_amdgcn_mfma_f32_16x16x32_bf16(a10,bf0,acc[1][nt],0,0,0);
      acc[1][nt]=__builtin_amdgcn_mfma_f32_16x16x32_bf16(a11,bf1,acc[1][nt],0,0,0);
    }
    // epilogue per node (single 4B gather per (nt,r): h2=low, h4=high)
    #pragma unroll
    for (int u=0;u<2;u++){
      int n = n0+u;
      size_t bn = u? b1 : b0;
      short* Au = u? A1 : A0;
      int dei[4];
      if (u==0){ dei[0]=de0.x; dei[1]=de0.y; dei[2]=de0.z; dei[3]=de0.w; }
      else     { dei[0]=de1.x; dei[1]=de1.y; dei[2]=de1.z; dei[3]=de1.w; }
      #pragma unroll
      for (int nt=0;nt<3;nt++){
        int c = nt*16+lrow;
        f32x4 ac = acc[u][nt];
        float bv = ebL[c];
        float h3v = hs2f(h3b[(size_t)n*48+c]);
        float pT=0.f, pT2=0.f, pM=0.f;
        #pragma unroll
        for (int r=0;r<4;r++){
          int e = quad*4+r;
          union { unsigned uu; short2 ss; } gpair;
          gpair.uu = *(const unsigned*)&h24[(size_t)dei[r]*96 + c*2];
          float h2v = hs2f(gpair.ss.x);
          float h4v = hs2f(gpair.ss.y);
          float t = ac[r] + bv + h3v + h4v;
          tmp[bn + e*48 + c] = f2hs(t);
          pT += t; pT2 += t*t;
          float gate = bs2f(Au[e*RPA+c]);
          pM += h2v * sigm(gate);
        }
        pT  += __shfl_xor(pT,16);  pT  += __shfl_xor(pT,32);
        pT2 += __shfl_xor(pT2,16); pT2 += __shfl_xor(pT2,32);
        pM  += __shfl_xor(pM,16);  pM  += __shfl_xor(pM,32);
        accT[nt] += pT; accT2[nt] += pT2;
        if (u==0){
          if (lane<16){
            float yv = h1[(size_t)n*48+c] + pM*(1.f/16.f);
            h1[(size_t)n*48+c] = yv;
            accY[nt] += yv; accY2[nt] += yv*yv;
          }
        } else {
          if (lane>=16 && lane<32){
            float yv = h1[(size_t)n*48+c] + pM*(1.f/16.f);
            h1[(size_t)n*48+c] = yv;
            accY[nt] += yv; accY2[nt] += yv*yv;
          }
        }
      }
    }
  }
  #pragma unroll
  for (int nt=0;nt<3;nt++){
    accY[nt]  += __shfl_xor(accY[nt],16);
    accY2[nt] += __shfl_xor(accY2[nt],16);
  }
  if (lane<16){
    #pragma unroll
    for (int nt=0;nt<3;nt++){
      int c = nt*16+lane;
      sACC[wid][c]      = accY[nt];
      sACC[wid][48+c]   = accY2[nt];
      sACC[wid][96+c]   = accT[nt];
      sACC[wid][144+c]  = accT2[nt];
    }
  }
  __syncthreads();
  if (tid<192){
    float s = sACC[0][tid]+sACC[1][tid]+sACC[2][tid]+sACC[3][tid];
    int bk = (blockIdx.x&63)*96;
    if (tid<96) atomicAdd(&myStats[bk+tid], s);
    else        atomicAdd(&myStats[6144+bk+(tid-96)], s);
  }
}

// ---------------- head 1: final e-BN + p1 GEMM + z GEMM ----------------
__global__ __launch_bounds__(256) void k_head1(
    const short* __restrict__ w, short* __restrict__ tmp,
    const void* __restrict__ pW0, const void* __restrict__ pb0,
    const void* __restrict__ zW0, const void* __restrict__ zb0,
    const void* __restrict__ zW1,
    const void* __restrict__ ge, const void* __restrict__ be,
    const float* __restrict__ stats, float* __restrict__ zpart,
    const void* __restrict__ fl)
{
  const bool isb = dflag(fl);
  __shared__ alignas(16) short BT0[48*RP];
  __shared__ alignas(16) short BT1[48*RP];
  __shared__ alignas(16) short AT[4][16*RP];
  __shared__ float pb0L[UU], zb0L[UU], zW1L[UU];
  __shared__ float scE[96];
  __shared__ float sred[96];
  __shared__ float zS[4];
  int tid = threadIdx.x, lane = tid&63, wid = tid>>6;
  stageW(BT0, pW0, 0, isb, tid);
  stageW(BT1, zW0, 0, isb, tid);
  for (int i=tid;i<768;i+=256){ int r=i/16,k=48+(i%16); BT0[r*RP+k]=0; BT1[r*RP+k]=0; }
  for (int i=tid;i<4*256;i+=256){ int wv=i/256, j=i%256; int r=j/16,k=48+(j%16); AT[wv][r*RP+k]=0; }
  if (tid<48){ pb0L[tid]=ldx(pb0,tid,isb); zb0L[tid]=ldx(zb0,tid,isb); zW1L[tid]=ldx(zW1,tid,isb); }
  if (tid<96){
    const float* sp = stats + (size_t)(DD-1)*12288 + 6144;
    float s=0.f;
    for (int k2=0;k2<64;k2++) s += sp[k2*96+tid];
    sred[tid]=s;
  }
  __syncthreads();
  if (tid<48){
    float mean = sred[tid]/(float)EE;
    float var = sred[48+tid]/(float)EE - mean*mean; if (var<0.f) var=0.f;
    float sc = ldx(ge,(size_t)(DD-1)*48+tid,isb) * rsqrtf(var+EPSBN);
    scE[tid]=sc; scE[48+tid]=ldx(be,(size_t)(DD-1)*48+tid,isb) - mean*sc;
  }
  __syncthreads();

  int quad = lane>>4, lrow = lane&15;
  short* A = AT[wid];
  float zacc = 0.f;
  int gw = blockIdx.x*4+wid, gws = gridDim.x*4;
  for (int n=gw; n<NN; n+=gws){
    size_t basef = (size_t)n*768;
    #pragma unroll
    for (int j=0;j<2;j++){
      int idx = lane + 64*j;
      if (idx < 96){
        int r = idx/6, c0 = (idx%6)*8;
        sx8 w8 = *(const sx8*)&w[basef + r*48 + c0];
        sx8 t8 = *(const sx8*)&tmp[basef + r*48 + c0];
        sx8 a8;
        #pragma unroll
        for (int q=0;q<8;q++){
          float f = hs2f(w8[q]) + siluf(scE[c0+q]*hs2f(t8[q]) + scE[48+c0+q]);
          a8[q] = f2bs(f);
        }
        *(sx8*)&A[r*RP + c0] = a8;
      }
    }
    LDSFENCE();
    bf16x8 a0 = *(const bf16x8*)&A[lrow*RP + quad*8];
    bf16x8 a1 = *(const bf16x8*)&A[lrow*RP + 32 + quad*8];
    f32x4 p0={0,0,0,0}, p1={0,0,0,0}, p2={0,0,0,0};
    f32x4 z0={0,0,0,0}, z1={0,0,0,0}, z2={0,0,0,0};
    bf16x8 bfr;
    bfr=*(const bf16x8*)&BT0[(0+lrow)*RP+quad*8];       p0=__builtin_amdgcn_mfma_f32_16x16x32_bf16(a0,bfr,p0,0,0,0);
    bfr=*(const bf16x8*)&BT0[(0+lrow)*RP+32+quad*8];    p0=__builtin_amdgcn_mfma_f32_16x16x32_bf16(a1,bfr,p0,0,0,0);
    bfr=*(const bf16x8*)&BT0[(16+lrow)*RP+quad*8];      p1=__builtin_amdgcn_mfma_f32_16x16x32_bf16(a0,bfr,p1,0,0,0);
    bfr=*(const bf16x8*)&BT0[(16+lrow)*RP+32+quad*8];   p1=__builtin_amdgcn_mfma_f32_16x16x32_bf16(a1,bfr,p1,0,0,0);
    bfr=*(const bf16x8*)&BT0[(32+lrow)*RP+quad*8];      p2=__builtin_amdgcn_mfma_f32_16x16x32_bf16(a0,bfr,p2,0,0,0);
    bfr=*(const bf16x8*)&BT0[(32+lrow)*RP+32+quad*8];   p2=__builtin_amdgcn_mfma_f32_16x16x32_bf16(a1,bfr,p2,0,0,0);
    bfr=*(const bf16x8*)&BT1[(0+lrow)*RP+quad*8];       z0=__builtin_amdgcn_mfma_f32_16x16x32_bf16(a0,bfr,z0,0,0,0);
    bfr=*(const bf16x8*)&BT1[(0+lrow)*RP+32+quad*8];    z0=__builtin_amdgcn_mfma_f32_16x16x32_bf16(a1,bfr,z0,0,0,0);
    bfr=*(const bf16x8*)&BT1[(16+lrow)*RP+quad*8];      z1=__builtin_amdgcn_mfma_f32_16x16x32_bf16(a0,bfr,z1,0,0,0);
    bfr=*(const bf16x8*)&BT1[(16+lrow)*RP+32+quad*8];   z1=__builtin_amdgcn_mfma_f32_16x16x32_bf16(a1,bfr,z1,0,0,0);
    bfr=*(const bf16x8*)&BT1[(32+lrow)*RP+quad*8];      z2=__builtin_amdgcn_mfma_f32_16x16x32_bf16(a0,bfr,z2,0,0,0);
    bfr=*(const bf16x8*)&BT1[(32+lrow)*RP+32+quad*8];   z2=__builtin_amdgcn_mfma_f32_16x16x32_bf16(a1,bfr,z2,0,0,0);
    #pragma unroll
    for (int nt=0;nt<3;nt++){
      int c = nt*16+lrow;
      f32x4 pp = (nt==0)?p0:((nt==1)?p1:p2);
      f32x4 zz = (nt==0)?z0:((nt==1)?z1:z2);
      float pb = pb0L[c], zb = zb0L[c], zw = zW1L[c];
      #pragma unroll
      for (int r=0;r<4;r++){
        int e = quad*4+r;
        tmp[basef + e*48 + c] = f2bs(siluf(pp[r] + pb));  // p1 bf16 (head2 MFMA A operand)
        float zr = zz[r] + zb;
        zacc += zw * (zr > 0.f ? zr : 0.f);
      }
    }
  }
  zacc += __shfl_xor(zacc,1); zacc += __shfl_xor(zacc,2); zacc += __shfl_xor(zacc,4);
  zacc += __shfl_xor(zacc,8); zacc += __shfl_xor(zacc,16); zacc += __shfl_xor(zacc,32);
  if (lane==0) zS[wid]=zacc;
  __syncthreads();
  if (tid==0) atomicAdd(&zpart[blockIdx.x&63], zS[0]+zS[1]+zS[2]+zS[3]);
}

// ---------------- head 2: p2 GEMM + scalar head + group softmax ----------------
__global__ __launch_bounds__(256) void k_head2(
    const short* __restrict__ tmp,
    const void* __restrict__ pW1, const void* __restrict__ pb1,
    const void* __restrict__ pW2,
    void* __restrict__ out, const void* __restrict__ fl)
{
  const bool isb = dflag(fl);
  __shared__ alignas(16) short BT[48*RP];
  __shared__ alignas(16) short AT[4][16*RP];
  __shared__ float pb1L[UU], pW2L[UU];
  int tid = threadIdx.x, lane = tid&63, wid = tid>>6;
  stageW(BT, pW1, 0, isb, tid);
  for (int i=tid;i<768;i+=256){ int r=i/16,k=48+(i%16); BT[r*RP+k]=0; }
  for (int i=tid;i<4*256;i+=256){ int wv=i/256, j=i%256; int r=j/16,k=48+(j%16); AT[wv][r*RP+k]=0; }
  if (tid<48){ pb1L[tid]=ldx(pb1,tid,isb); pW2L[tid]=ldx(pW2,tid,isb); }
  __syncthreads();

  int quad = lane>>4, lrow = lane&15;
  short* A = AT[wid];
  int gw = blockIdx.x*4+wid, gws = gridDim.x*4;
  for (int n=gw; n<NN; n+=gws){
    size_t basef = (size_t)n*768;
    #pragma unroll
    for (int j=0;j<2;j++){
      int idx = lane + 64*j;
      if (idx < 96){
        int r = idx/6, c8 = idx%6;
        *(bf16x8*)&A[r*RP + c8*8] = *(const bf16x8*)&tmp[basef + r*48 + c8*8];
      }
    }
    LDSFENCE();
    bf16x8 a0 = *(const bf16x8*)&A[lrow*RP + quad*8];
    bf16x8 a1 = *(const bf16x8*)&A[lrow*RP + 32 + quad*8];
    f32x4 q0={0,0,0,0}, q1={0,0,0,0}, q2={0,0,0,0};
    bf16x8 bfr;
    bfr=*(const bf16x8*)&BT[(0+lrow)*RP+quad*8];       q0=__builtin_amdgcn_mfma_f32_16x16x32_bf16(a0,bfr,q0,0,0,0);
    bfr=*(const bf16x8*)&BT[(0+lrow)*RP+32+quad*8];    q0=__builtin_amdgcn_mfma_f32_16x16x32_bf16(a1,bfr,q0,0,0,0);
    bfr=*(const bf16x8*)&BT[(16+lrow)*RP+quad*8];      q1=__builtin_amdgcn_mfma_f32_16x16x32_bf16(a0,bfr,q1,0,0,0);
    bfr=*(const bf16x8*)&BT[(16+lrow)*RP+32+quad*8];   q1=__builtin_amdgcn_mfma_f32_16x16x32_bf16(a1,bfr,q1,0,0,0);
    bfr=*(const bf16x8*)&BT[(32+lrow)*RP+quad*8];      q2=__builtin_amdgcn_mfma_f32_16x16x32_bf16(a0,bfr,q2,0,0,0);
    bfr=*(const bf16x8*)&BT[(32+lrow)*RP+32+quad*8];   q2=__builtin_amdgcn_mfma_f32_16x16x32_bf16(a1,bfr,q2,0,0,0);
    float pp[4] = {0.f,0.f,0.f,0.f};
    #pragma unroll
    for (int nt=0;nt<3;nt++){
      int c = nt*16+lrow;
      f32x4 qq = (nt==0)?q0:((nt==1)?q1:q2);
      float pb = pb1L[c], pw = pW2L[c];
      #pragma unroll
      for (int r=0;r<4;r++) pp[r] += pw * siluf(qq[r] + pb);
    }
    #pragma unroll
    for (int r=0;r<4;r++){
      pp[r] += __shfl_xor(pp[r],1); pp[r] += __shfl_xor(pp[r],2);
      pp[r] += __shfl_xor(pp[r],4); pp[r] += __shfl_xor(pp[r],8);
    }
    float mx = fmaxf(fmaxf(pp[0],pp[1]), fmaxf(pp[2],pp[3]));
    mx = fmaxf(mx, __shfl_xor(mx,16)); mx = fmaxf(mx, __shfl_xor(mx,32));
    float ex[4]; float se = 0.f;
    #pragma unroll
    for (int r=0;r<4;r++){ ex[r] = __expf(pp[r]-mx); se += ex[r]; }
    se += __shfl_xor(se,16); se += __shfl_xor(se,32);
    float inv = 1.f/se;
    if (lrow==0){
      #pragma unroll
      for (int r=0;r<4;r++) stout(out, (size_t)n*16 + quad*4 + r, ex[r]*inv, isb);
    }
  }
}

__global__ void k_final(const float* __restrict__ zpart, const void* __restrict__ zb1,
                        void* __restrict__ out, const void* __restrict__ fl){
  const bool isb = dflag(fl);
  int tid=threadIdx.x;
  float s = (tid<64) ? zpart[tid] : 0.f;
  s += __shfl_xor(s,1); s += __shfl_xor(s,2); s += __shfl_xor(s,4);
  s += __shfl_xor(s,8); s += __shfl_xor(s,16); s += __shfl_xor(s,32);
  if (tid==0) stout(out, EE, s/(float)EE + ldx(zb1,0,isb), isb);
}

extern "C" void kernel_launch(void* const* d_in, const int* in_sizes, int n_in,
                              void* d_out, int out_size, void* d_ws, size_t ws_size,
                              hipStream_t stream){
  (void)in_sizes; (void)n_in; (void)out_size; (void)ws_size;
  const void* x=d_in[0]; const void* ea=d_in[1];
  const int* ei=(const int*)d_in[2];
  const void* vW0=d_in[3]; const void* vb0=d_in[4];
  const void* vW1=d_in[5]; const void* vW2=d_in[6]; const void* vW3=d_in[7]; const void* vW4=d_in[8];
  const void* vb1=d_in[9]; const void* vb2=d_in[10]; const void* vb3=d_in[11]; const void* vb4=d_in[12];
  const void* vbng=d_in[13]; const void* vbnb=d_in[14];
  const void* eW0=d_in[15]; const void* eb0=d_in[16];
  const void* eW=d_in[17]; const void* ebv=d_in[18];
  const void* ebng=d_in[19]; const void* ebnb=d_in[20];
  const void* pW0=d_in[21]; const void* pb0=d_in[22];
  const void* pW1=d_in[23]; const void* pb1=d_in[24];
  const void* pW2=d_in[25]; const void* pb2=d_in[26]; (void)pb2; // cancels in softmax
  const void* zW0=d_in[27]; const void* zb0=d_in[28];
  const void* zW1=d_in[29]; const void* zb1=d_in[30];
  const int* dst = ei + EE;
  const void* fl = vbng;

  float* h   = (float*)d_ws;                       // [N,48] f32
  float* h1  = h  + (size_t)NN*UU;                 // [N,48] f32
  short* h24 = (short*)(h1 + (size_t)NN*UU);       // [N,96] f16 interleaved h2/h4
  short* h3b = h24 + (size_t)NN*96;                // [N,48] f16
  short* w   = h3b + (size_t)NN*UU;                // [E,48] f16 (residual trunk)
  short* tmp = w + (size_t)EE*UU;                  // [E,48] f16 t (head1 stores bf16 p1)
  float* stats = (float*)(tmp + (size_t)EE*UU);    // 12 layers x 12288
  float* zpart = stats + DD*12288;

  k_init_nodes<<<(NN*UU+255)/256,256,0,stream>>>(x,vW0,vb0,h,stats,zpart,fl);
  k_init_edges<<<(EE*UU+255)/256,256,0,stream>>>(ea,eW0,eb0,w,fl);
  for (int d=0; d<DD; d++){
    int ctl = (d<<1) | (d>0 ? 1 : 0);
    k_node<<<512,256,0,stream>>>(h,h1,h24,h3b,
        vW1,vW2,vW3,vW4,vb1,vb2,vb3,vb4,vbng,vbnb,stats,ctl,fl);
    // grid 1280: LDS ~31KB permits 5 blocks/CU; VGPR cap 128 (bounds 256,4) avoids spills
    k_edge<<<1280,256,0,stream>>>(w,tmp,h1,h24,h3b,dst,eW,ebv,ebng,ebnb,stats,ctl,fl);
  }
  k_head1<<<1024,256,0,stream>>>(w,tmp,pW0,pb0,zW0,zb0,zW1,ebng,ebnb,stats,zpart,fl);
  k_head2<<<1024,256,0,stream>>>(tmp,pW1,pb1,pW2,d_out,fl);
  k_final<<<1,64,0,stream>>>(zpart,zb1,d_out,fl);
}